// Round 3
// baseline (624.443 us; speedup 1.0000x reference)
//
#include <hip/hip_runtime.h>
#include <math.h>

#define CI 256
#define CO 256
#define HWN 4096  // H*W

typedef short bf16x8 __attribute__((ext_vector_type(8)));
typedef float f32x4 __attribute__((ext_vector_type(4)));

__device__ inline unsigned pk2(float a, float b) {  // RNE pack 2 f32 -> 2 bf16
  unsigned ua = __float_as_uint(a), ub = __float_as_uint(b);
  ua += 0x7fff + ((ua >> 16) & 1);
  ub += 0x7fff + ((ub >> 16) & 1);
  return (ua >> 16) | (ub & 0xffff0000u);
}

// ---------------------------------------------------------------------------
// Kernel 0: weight pre-transpose+convert: w[o][c][tap] f32 -> wT[tap][o][c] bf16
// ---------------------------------------------------------------------------
__global__ __launch_bounds__(256) void k_wprep(const float* __restrict__ wgt,
                                               unsigned short* __restrict__ wT) {
  const int o = blockIdx.x, c = threadIdx.x;
  const float* wp = wgt + o * 2304 + c * 9;
  float v[9];
#pragma unroll
  for (int t = 0; t < 9; ++t) v[t] = wp[t];
#pragma unroll
  for (int t = 0; t < 9; ++t) {
    unsigned u = __float_as_uint(v[t]);
    u += 0x7fff + ((u >> 16) & 1);
    wT[(t << 16) + (o << 8) + c] = (unsigned short)(u >> 16);
  }
}

// ---------------------------------------------------------------------------
// Kernel 1: offset (18ch) + modulation (9ch) 3x3 conv over Ci=256.
// Now 512 threads / 8 waves per (b,h) row: wave g handles channels c=8t+g,
// 32 t-iters. x rows staged in LDS; weight loads wave-uniform -> scalar.
// ---------------------------------------------------------------------------
__global__ __launch_bounds__(512, 4) void k_offmod(
    const float* __restrict__ x, const float* __restrict__ ow,
    const float* __restrict__ ob, const float* __restrict__ mw,
    const float* __restrict__ mb, float* __restrict__ dyb,
    float* __restrict__ dxb, float* __restrict__ mskb) {
  __shared__ float xs[1584];   // 8 ch * 3 rows * 66 cols
  __shared__ float ps[13824];  // 64 px * 27 ch * 8 groups
  const int tid = threadIdx.x;
  const int bh = blockIdx.x;
  const int b = bh >> 6, h = bh & 63;
  const int cg = __builtin_amdgcn_readfirstlane(tid >> 6);  // wave id 0..7
  const int px = tid & 63;
  float acc[27];
#pragma unroll
  for (int i = 0; i < 27; ++i) acc[i] = 0.f;
  const float* xb = x + b * (CI * HWN);
  for (int t = 0; t < 32; ++t) {
    __syncthreads();
    for (int i = tid; i < 1584; i += 512) {
      int cl = i / 198;
      int rem = i - cl * 198;
      int r = rem / 66;
      int col = rem - r * 66 - 1;
      int hh = h - 1 + r;
      float v = 0.f;
      if (hh >= 0 && hh < 64 && col >= 0 && col < 64)
        v = xb[(8 * t + cl) * HWN + hh * 64 + col];
      xs[i] = v;
    }
    __syncthreads();
    float xv[9];
#pragma unroll
    for (int r = 0; r < 3; ++r)
#pragma unroll
      for (int kx = 0; kx < 3; ++kx)
        xv[r * 3 + kx] = xs[cg * 198 + r * 66 + px + kx];
    const int c = 8 * t + cg;
    const float* owp = ow + c * 9;
    const float* mwp = mw + c * 9;
#pragma unroll
    for (int ch = 0; ch < 18; ++ch)
#pragma unroll
      for (int k = 0; k < 9; ++k)
        acc[ch] = fmaf(owp[ch * 2304 + k], xv[k], acc[ch]);
#pragma unroll
    for (int ch = 0; ch < 9; ++ch)
#pragma unroll
      for (int k = 0; k < 9; ++k)
        acc[18 + ch] = fmaf(mwp[ch * 2304 + k], xv[k], acc[18 + ch]);
  }
  __syncthreads();
#pragma unroll
  for (int ch = 0; ch < 27; ++ch) ps[(px * 27 + ch) * 8 + cg] = acc[ch];
  __syncthreads();
  for (int i = tid; i < 1728; i += 512) {
    int p2 = i / 27;
    int ch = i - p2 * 27;
    float s = 0.f;
#pragma unroll
    for (int g = 0; g < 8; ++g) s += ps[i * 8 + g];
    if (ch < 18) {
      s += ob[ch];
      int k = ch >> 1;
      int o9 = ((b * 9 + k) << 12) + (h << 6) + p2;
      if ((ch & 1) == 0) dyb[o9] = s;
      else dxb[o9] = s;
    } else {
      int k = ch - 18;
      s += mb[k];
      mskb[((b * 9 + k) << 12) + (h << 6) + p2] = 2.f / (1.f + expf(-s));
    }
  }
}

// ---------------------------------------------------------------------------
// Kernel 2: bf16-MFMA gather-GEMM, tap-major K order.
// K permuted as (tap, c): chunk = 1 tap x 64 channels (9 taps x 4 cq = 36).
// Corner weights/indices live in registers across each tap (no div, no
// per-sample table reads); corner addresses advance linearly in c.
// B chunks are coalesced copies of pre-transposed bf16 wT[tap][o][c].
// LDS 49 KB -> 3 blocks/CU, launch_bounds(512,6) -> 24 waves/CU.
// ---------------------------------------------------------------------------
__global__ __launch_bounds__(512, 6) void k_main(
    const float* __restrict__ x, const unsigned short* __restrict__ wT,
    const float* __restrict__ dyb, const float* __restrict__ dxb,
    const float* __restrict__ mskb, float* __restrict__ out,
    float* __restrict__ psum, float* __restrict__ psq) {
  __shared__ __align__(16) char smem[50176];
  uint2* s_cw = (uint2*)smem;               // [9][64] 4x bf16 corner w, 4608 B
  ushort4* s_ci = (ushort4*)(smem + 4608);  // [9][64] corner idx, 4608 B
  char* sA = smem + 9216;                   // 64x64 bf16 = 8192 B
  char* sB = smem + 17408;                  // 256x64 bf16 = 32768 B
  float* tr = (float*)(smem + 9216);        // epilogue reuse: 128*65*4 B

  const int tid = threadIdx.x;
  const int mblk = blockIdx.x;  // b*64 + h
  const int b = mblk >> 6, h = mblk & 63;
  const int lane = tid & 63;
  const int wv = tid >> 6;

  // ---- corner table: 9 taps * 64 px ----
  for (int i = tid; i < 576; i += 512) {
    int k = i >> 6, pxi = i & 63;
    int o9 = ((b * 9 + k) << 12) + (h << 6) + pxi;
    float m = mskb[o9];
    float py = (float)(h - 1 + k / 3) + dyb[o9];
    float pxf = (float)(pxi - 1 + k % 3) + dxb[o9];
    float y0f = floorf(py), x0f = floorf(pxf);
    float wy = py - y0f, wx = pxf - x0f;
    int y0 = (int)y0f, x0 = (int)x0f;
    int y1 = y0 + 1, x1 = x0 + 1;
    float w00 = (1.f - wy) * (1.f - wx) * m;
    float w01 = (1.f - wy) * wx * m;
    float w10 = wy * (1.f - wx) * m;
    float w11 = wy * wx * m;
    bool vy0 = ((unsigned)y0 < 64u), vy1 = ((unsigned)y1 < 64u);
    bool vx0 = ((unsigned)x0 < 64u), vx1 = ((unsigned)x1 < 64u);
    if (!(vy0 && vx0)) w00 = 0.f;
    if (!(vy0 && vx1)) w01 = 0.f;
    if (!(vy1 && vx0)) w10 = 0.f;
    if (!(vy1 && vx1)) w11 = 0.f;
    int y0c = min(max(y0, 0), 63), y1c = min(max(y1, 0), 63);
    int x0c = min(max(x0, 0), 63), x1c = min(max(x1, 0), 63);
    s_cw[i] = make_uint2(pk2(w00, w01), pk2(w10, w11));
    s_ci[i] = make_ushort4((unsigned short)(y0c * 64 + x0c),
                           (unsigned short)(y0c * 64 + x1c),
                           (unsigned short)(y1c * 64 + x0c),
                           (unsigned short)(y1c * 64 + x1c));
  }
  __syncthreads();

  f32x4 acc[4][2];
#pragma unroll
  for (int mf = 0; mf < 4; ++mf)
#pragma unroll
    for (int nf = 0; nf < 2; ++nf) acc[mf][nf] = (f32x4){0.f, 0.f, 0.f, 0.f};

  const float* xb = x + b * (CI * HWN);
  const int aslot = (lane << 7) + ((wv ^ (lane & 7)) << 4);

  for (int tap = 0; tap < 9; ++tap) {
    // hoist this tap's corner data into registers (wave-uniform tap)
    float4 cw;
    ushort4 ci4;
    {
      uint2 p = s_cw[(tap << 6) + lane];
      cw.x = __uint_as_float(p.x << 16);
      cw.y = __uint_as_float(p.x & 0xffff0000u);
      cw.z = __uint_as_float(p.y << 16);
      cw.w = __uint_as_float(p.y & 0xffff0000u);
      ci4 = s_ci[(tap << 6) + lane];
    }
    const unsigned short* wTt = wT + (tap << 16);
#pragma unroll 1
    for (int cq = 0; cq < 4; ++cq) {
      __syncthreads();  // previous chunk's fragment reads complete
      // ---- stage A: 8 channels of this tap per thread, px = lane ----
      {
        const float* xp0 = xb + (((cq << 3) + wv) << 3) * HWN;
        unsigned pkv[4];
#pragma unroll
        for (int j2 = 0; j2 < 4; ++j2) {
          float vv[2];
#pragma unroll
          for (int u = 0; u < 2; ++u) {
            const float* xp = xp0 + (j2 * 2 + u) * HWN;
            float v = cw.x * xp[ci4.x];
            v = fmaf(cw.y, xp[ci4.y], v);
            v = fmaf(cw.z, xp[ci4.z], v);
            vv[u] = fmaf(cw.w, xp[ci4.w], v);
          }
          pkv[j2] = pk2(vv[0], vv[1]);
        }
        *(uint4*)(sA + aslot) = make_uint4(pkv[0], pkv[1], pkv[2], pkv[3]);
      }
      // ---- stage B: coalesced copy wT[tap][0..255][cq*64..+64] ----
      {
        const unsigned short* wp = wTt + (cq << 6);
#pragma unroll
        for (int r = 0; r < 4; ++r) {
          int idx = (r << 9) + tid;  // 0..2047
          int o = idx >> 3, seg = idx & 7;
          uint4 v = *(const uint4*)(wp + (o << 8) + (seg << 3));
          int slot = seg ^ (o & 7);
          *(uint4*)(sB + (o << 7) + (slot << 4)) = v;
        }
      }
      __syncthreads();
      // ---- MFMA: 2 k-steps x 4 mfrag x 2 nfrag ----
#pragma unroll
      for (int ks = 0; ks < 2; ++ks) {
        bf16x8 af[4], bfr[2];
#pragma unroll
        for (int mf = 0; mf < 4; ++mf) {
          int row = (mf << 4) + (lane & 15);
          int slot = ((ks << 2) + (lane >> 4)) ^ (row & 7);
          af[mf] = *(bf16x8*)(sA + (row << 7) + (slot << 4));
        }
#pragma unroll
        for (int nf = 0; nf < 2; ++nf) {
          int row = (wv << 5) + (nf << 4) + (lane & 15);
          int slot = ((ks << 2) + (lane >> 4)) ^ (row & 7);
          bfr[nf] = *(bf16x8*)(sB + (row << 7) + (slot << 4));
        }
#pragma unroll
        for (int mf = 0; mf < 4; ++mf)
#pragma unroll
          for (int nf = 0; nf < 2; ++nf)
            acc[mf][nf] = __builtin_amdgcn_mfma_f32_16x16x32_bf16(
                af[mf], bfr[nf], acc[mf][nf], 0, 0, 0);
      }
    }
  }

  // ---- BN partial stats from registers ----
#pragma unroll
  for (int nf = 0; nf < 2; ++nf) {
    float s = 0.f, q = 0.f;
#pragma unroll
    for (int mf = 0; mf < 4; ++mf)
#pragma unroll
      for (int r = 0; r < 4; ++r) {
        float v = acc[mf][nf][r];
        s += v;
        q = fmaf(v, v, q);
      }
    s += __shfl_down(s, 32);
    q += __shfl_down(q, 32);
    s += __shfl_down(s, 16);
    q += __shfl_down(q, 16);
    if (lane < 16) {
      int o = (wv << 5) + (nf << 4) + lane;
      psum[(o << 9) + mblk] = s;
      psq[(o << 9) + mblk] = q;
    }
  }

  // ---- store via LDS transpose, 2 passes of 128 o-rows ----
  __syncthreads();
  for (int p = 0; p < 2; ++p) {
    if ((wv >> 2) == p) {
#pragma unroll
      for (int mf = 0; mf < 4; ++mf)
#pragma unroll
        for (int nf = 0; nf < 2; ++nf) {
          int ro = ((wv & 3) << 5) + (nf << 4) + (lane & 15);
#pragma unroll
          for (int r = 0; r < 4; ++r)
            tr[ro * 65 + (mf << 4) + ((lane >> 4) << 2) + r] = acc[mf][nf][r];
        }
    }
    __syncthreads();
#pragma unroll
    for (int it = 0; it < 4; ++it) {
      int idx = tid + (it << 9);
      int ro = idx >> 4, qd = idx & 15;
      float4 v = make_float4(tr[ro * 65 + qd * 4], tr[ro * 65 + qd * 4 + 1],
                             tr[ro * 65 + qd * 4 + 2], tr[ro * 65 + qd * 4 + 3]);
      *(float4*)(out + (((b << 8) + (p << 7) + ro) << 12) + (h << 6) +
                 (qd << 2)) = v;
    }
    __syncthreads();
  }
}

// ---------------------------------------------------------------------------
// Kernel 3: per-channel stats -> scale/shift (512 partials per channel).
// ---------------------------------------------------------------------------
__global__ __launch_bounds__(64) void k_stats(
    const float* __restrict__ psum, const float* __restrict__ psq,
    const float* __restrict__ gamma, const float* __restrict__ beta,
    float* __restrict__ scale, float* __restrict__ shift) {
  const int o = blockIdx.x;
  const int t = threadIdx.x;
  float s = 0.f, q = 0.f;
#pragma unroll
  for (int i = 0; i < 8; ++i) {
    s += psum[(o << 9) + t + (i << 6)];
    q += psq[(o << 9) + t + (i << 6)];
  }
#pragma unroll
  for (int off = 32; off > 0; off >>= 1) {
    s += __shfl_down(s, off, 64);
    q += __shfl_down(q, off, 64);
  }
  if (t == 0) {
    const float inv_n = 1.f / 32768.f;
    float mean = s * inv_n;
    float var = fmaf(-mean, mean, q * inv_n);
    float sc = gamma[o] * rsqrtf(var + 1e-5f);
    scale[o] = sc;
    shift[o] = fmaf(-mean, sc, beta[o]);
  }
}

// ---------------------------------------------------------------------------
// Kernel 4: in-place BN + ReLU over d_out (float4 elementwise).
// ---------------------------------------------------------------------------
__global__ __launch_bounds__(256) void k_bnrelu(
    float* __restrict__ out, const float* __restrict__ scale,
    const float* __restrict__ shift) {
  int idx = blockIdx.x * 256 + threadIdx.x;
  int o = (idx >> 10) & 255;
  float sc = scale[o], sh = shift[o];
  float4 v = ((float4*)out)[idx];
  v.x = fmaxf(fmaf(v.x, sc, sh), 0.f);
  v.y = fmaxf(fmaf(v.y, sc, sh), 0.f);
  v.z = fmaxf(fmaf(v.z, sc, sh), 0.f);
  v.w = fmaxf(fmaf(v.w, sc, sh), 0.f);
  ((float4*)out)[idx] = v;
}

extern "C" void kernel_launch(void* const* d_in, const int* in_sizes, int n_in,
                              void* d_out, int out_size, void* d_ws,
                              size_t ws_size, hipStream_t stream) {
  const float* x = (const float*)d_in[0];
  const float* ow = (const float*)d_in[1];
  const float* ob = (const float*)d_in[2];
  const float* mw = (const float*)d_in[3];
  const float* mb = (const float*)d_in[4];
  const float* wgt = (const float*)d_in[5];
  // d_in[6] = conv bias: cancels exactly in BN (out - mean(out)), skipped.
  const float* gamma = (const float*)d_in[7];
  const float* beta = (const float*)d_in[8];
  float* out = (float*)d_out;

  float* ws = (float*)d_ws;
  float* dyb = ws;                  // 294912
  float* dxb = dyb + 294912;        // 294912
  float* mskb = dxb + 294912;       // 294912
  float* psum = mskb + 294912;      // 256*512 = 131072
  float* psq = psum + 131072;       // 131072
  float* scale = psq + 131072;      // 256
  float* shift = scale + 256;       // 256
  unsigned short* wT = (unsigned short*)(shift + 256);  // 9*256*256 bf16

  k_wprep<<<256, 256, 0, stream>>>(wgt, wT);
  k_offmod<<<512, 512, 0, stream>>>(x, ow, ob, mw, mb, dyb, dxb, mskb);
  k_main<<<512, 512, 0, stream>>>(x, wT, dyb, dxb, mskb, out, psum, psq);
  k_stats<<<256, 64, 0, stream>>>(psum, psq, gamma, beta, scale, shift);
  k_bnrelu<<<8192, 256, 0, stream>>>(out, scale, shift);
}

// Round 4
// 372.795 us; speedup vs baseline: 1.6750x; 1.6750x over previous
//
#include <hip/hip_runtime.h>
#include <math.h>

#define CI 256
#define CO 256
#define HWN 4096  // H*W

typedef short bf16x8 __attribute__((ext_vector_type(8)));
typedef float f32x4 __attribute__((ext_vector_type(4)));

__device__ inline unsigned pk2(float a, float b) {  // RNE pack 2 f32 -> 2 bf16
  unsigned ua = __float_as_uint(a), ub = __float_as_uint(b);
  ua += 0x7fff + ((ua >> 16) & 1);
  ub += 0x7fff + ((ub >> 16) & 1);
  return (ua >> 16) | (ub & 0xffff0000u);
}

// ---------------------------------------------------------------------------
// Kernel 0: weight pre-transpose+convert: w[o][c][tap] f32 -> wT[tap][o][c] bf16
// ---------------------------------------------------------------------------
__global__ __launch_bounds__(256) void k_wprep(const float* __restrict__ wgt,
                                               unsigned short* __restrict__ wT) {
  const int o = blockIdx.x, c = threadIdx.x;
  const float* wp = wgt + o * 2304 + c * 9;
  float v[9];
#pragma unroll
  for (int t = 0; t < 9; ++t) v[t] = wp[t];
#pragma unroll
  for (int t = 0; t < 9; ++t) {
    unsigned u = __float_as_uint(v[t]);
    u += 0x7fff + ((u >> 16) & 1);
    wT[(t << 16) + (o << 8) + c] = (unsigned short)(u >> 16);
  }
}

// ---------------------------------------------------------------------------
// Kernel 1: offset (18ch) + modulation (9ch) 3x3 conv over Ci=256.
// 512 threads / 8 waves per (b,h) row: wave g handles channels c=8t+g,
// 32 t-iters. x rows staged in LDS; weight loads wave-uniform -> scalar.
// ---------------------------------------------------------------------------
__global__ __launch_bounds__(512, 4) void k_offmod(
    const float* __restrict__ x, const float* __restrict__ ow,
    const float* __restrict__ ob, const float* __restrict__ mw,
    const float* __restrict__ mb, float* __restrict__ dyb,
    float* __restrict__ dxb, float* __restrict__ mskb) {
  __shared__ float xs[1584];   // 8 ch * 3 rows * 66 cols
  __shared__ float ps[13824];  // 64 px * 27 ch * 8 groups
  const int tid = threadIdx.x;
  const int bh = blockIdx.x;
  const int b = bh >> 6, h = bh & 63;
  const int cg = __builtin_amdgcn_readfirstlane(tid >> 6);  // wave id 0..7
  const int px = tid & 63;
  float acc[27];
#pragma unroll
  for (int i = 0; i < 27; ++i) acc[i] = 0.f;
  const float* xb = x + b * (CI * HWN);
  for (int t = 0; t < 32; ++t) {
    __syncthreads();
    for (int i = tid; i < 1584; i += 512) {
      int cl = i / 198;
      int rem = i - cl * 198;
      int r = rem / 66;
      int col = rem - r * 66 - 1;
      int hh = h - 1 + r;
      float v = 0.f;
      if (hh >= 0 && hh < 64 && col >= 0 && col < 64)
        v = xb[(8 * t + cl) * HWN + hh * 64 + col];
      xs[i] = v;
    }
    __syncthreads();
    float xv[9];
#pragma unroll
    for (int r = 0; r < 3; ++r)
#pragma unroll
      for (int kx = 0; kx < 3; ++kx)
        xv[r * 3 + kx] = xs[cg * 198 + r * 66 + px + kx];
    const int c = 8 * t + cg;
    const float* owp = ow + c * 9;
    const float* mwp = mw + c * 9;
#pragma unroll
    for (int ch = 0; ch < 18; ++ch)
#pragma unroll
      for (int k = 0; k < 9; ++k)
        acc[ch] = fmaf(owp[ch * 2304 + k], xv[k], acc[ch]);
#pragma unroll
    for (int ch = 0; ch < 9; ++ch)
#pragma unroll
      for (int k = 0; k < 9; ++k)
        acc[18 + ch] = fmaf(mwp[ch * 2304 + k], xv[k], acc[18 + ch]);
  }
  __syncthreads();
#pragma unroll
  for (int ch = 0; ch < 27; ++ch) ps[(px * 27 + ch) * 8 + cg] = acc[ch];
  __syncthreads();
  for (int i = tid; i < 1728; i += 512) {
    int p2 = i / 27;
    int ch = i - p2 * 27;
    float s = 0.f;
#pragma unroll
    for (int g = 0; g < 8; ++g) s += ps[i * 8 + g];
    if (ch < 18) {
      s += ob[ch];
      int k = ch >> 1;
      int o9 = ((b * 9 + k) << 12) + (h << 6) + p2;
      if ((ch & 1) == 0) dyb[o9] = s;
      else dxb[o9] = s;
    } else {
      int k = ch - 18;
      s += mb[k];
      mskb[((b * 9 + k) << 12) + (h << 6) + p2] = 2.f / (1.f + expf(-s));
    }
  }
}

// ---------------------------------------------------------------------------
// Kernel 2: bf16-MFMA gather-GEMM.
// K chunk = (1 tap x 64 channels); loop nest = OUTER cq (channel quarter),
// INNER tap. Channel-quarter working set (~49 KB/block) is re-read across
// the 9 taps while L2-hot (per-XCD concurrent set ~3.1 MB < 4 MB L2), so x
// is fetched from HBM only once per channel -> FETCH ~130 MB (vs 1.17 GB
// with tap-outer order). Corner weights/indices hoisted to registers per
// tap step (2 ds_reads); B chunks are coalesced copies of bf16 wT[tap][o][c].
// ---------------------------------------------------------------------------
__global__ __launch_bounds__(512, 4) void k_main(
    const float* __restrict__ x, const unsigned short* __restrict__ wT,
    const float* __restrict__ dyb, const float* __restrict__ dxb,
    const float* __restrict__ mskb, float* __restrict__ out,
    float* __restrict__ psum, float* __restrict__ psq) {
  __shared__ __align__(16) char smem[50176];
  uint2* s_cw = (uint2*)smem;               // [9][64] 4x bf16 corner w, 4608 B
  ushort4* s_ci = (ushort4*)(smem + 4608);  // [9][64] corner idx, 4608 B
  char* sA = smem + 9216;                   // 64x64 bf16 = 8192 B
  char* sB = smem + 17408;                  // 256x64 bf16 = 32768 B
  float* tr = (float*)(smem + 9216);        // epilogue reuse: 128*65*4 B

  const int tid = threadIdx.x;
  const int mblk = blockIdx.x;  // b*64 + h
  const int b = mblk >> 6, h = mblk & 63;
  const int lane = tid & 63;
  const int wv = tid >> 6;

  // ---- corner table: 9 taps * 64 px ----
  for (int i = tid; i < 576; i += 512) {
    int k = i >> 6, pxi = i & 63;
    int o9 = ((b * 9 + k) << 12) + (h << 6) + pxi;
    float m = mskb[o9];
    float py = (float)(h - 1 + k / 3) + dyb[o9];
    float pxf = (float)(pxi - 1 + k % 3) + dxb[o9];
    float y0f = floorf(py), x0f = floorf(pxf);
    float wy = py - y0f, wx = pxf - x0f;
    int y0 = (int)y0f, x0 = (int)x0f;
    int y1 = y0 + 1, x1 = x0 + 1;
    float w00 = (1.f - wy) * (1.f - wx) * m;
    float w01 = (1.f - wy) * wx * m;
    float w10 = wy * (1.f - wx) * m;
    float w11 = wy * wx * m;
    bool vy0 = ((unsigned)y0 < 64u), vy1 = ((unsigned)y1 < 64u);
    bool vx0 = ((unsigned)x0 < 64u), vx1 = ((unsigned)x1 < 64u);
    if (!(vy0 && vx0)) w00 = 0.f;
    if (!(vy0 && vx1)) w01 = 0.f;
    if (!(vy1 && vx0)) w10 = 0.f;
    if (!(vy1 && vx1)) w11 = 0.f;
    int y0c = min(max(y0, 0), 63), y1c = min(max(y1, 0), 63);
    int x0c = min(max(x0, 0), 63), x1c = min(max(x1, 0), 63);
    s_cw[i] = make_uint2(pk2(w00, w01), pk2(w10, w11));
    s_ci[i] = make_ushort4((unsigned short)(y0c * 64 + x0c),
                           (unsigned short)(y0c * 64 + x1c),
                           (unsigned short)(y1c * 64 + x0c),
                           (unsigned short)(y1c * 64 + x1c));
  }
  __syncthreads();

  f32x4 acc[4][2];
#pragma unroll
  for (int mf = 0; mf < 4; ++mf)
#pragma unroll
    for (int nf = 0; nf < 2; ++nf) acc[mf][nf] = (f32x4){0.f, 0.f, 0.f, 0.f};

  const float* xb = x + b * (CI * HWN);
  const int aslot = (lane << 7) + ((wv ^ (lane & 7)) << 4);

#pragma unroll 1
  for (int cq = 0; cq < 4; ++cq) {
    const float* xq = xb + ((cq << 3) << 3) * HWN;  // + cq*64 channels
#pragma unroll 1
    for (int tap = 0; tap < 9; ++tap) {
      // hoist this tap's corner data into registers (wave-uniform tap)
      float4 cw;
      ushort4 ci4;
      {
        uint2 p = s_cw[(tap << 6) + lane];
        cw.x = __uint_as_float(p.x << 16);
        cw.y = __uint_as_float(p.x & 0xffff0000u);
        cw.z = __uint_as_float(p.y << 16);
        cw.w = __uint_as_float(p.y & 0xffff0000u);
        ci4 = s_ci[(tap << 6) + lane];
      }
      __syncthreads();  // previous chunk's fragment reads complete
      // ---- stage A: 8 channels of this tap per thread, px = lane ----
      {
        const float* xp0 = xq + (wv << 3) * HWN;
        unsigned pkv[4];
#pragma unroll
        for (int j2 = 0; j2 < 4; ++j2) {
          float vv[2];
#pragma unroll
          for (int u = 0; u < 2; ++u) {
            const float* xp = xp0 + (j2 * 2 + u) * HWN;
            float v = cw.x * xp[ci4.x];
            v = fmaf(cw.y, xp[ci4.y], v);
            v = fmaf(cw.z, xp[ci4.z], v);
            vv[u] = fmaf(cw.w, xp[ci4.w], v);
          }
          pkv[j2] = pk2(vv[0], vv[1]);
        }
        *(uint4*)(sA + aslot) = make_uint4(pkv[0], pkv[1], pkv[2], pkv[3]);
      }
      // ---- stage B: coalesced copy wT[tap][0..255][cq*64..+64] ----
      {
        const unsigned short* wp = wT + (tap << 16) + (cq << 6);
#pragma unroll
        for (int r = 0; r < 4; ++r) {
          int idx = (r << 9) + tid;  // 0..2047
          int o = idx >> 3, seg = idx & 7;
          uint4 v = *(const uint4*)(wp + (o << 8) + (seg << 3));
          int slot = seg ^ (o & 7);
          *(uint4*)(sB + (o << 7) + (slot << 4)) = v;
        }
      }
      __syncthreads();
      // ---- MFMA: 2 k-steps x 4 mfrag x 2 nfrag ----
#pragma unroll
      for (int ks = 0; ks < 2; ++ks) {
        bf16x8 af[4], bfr[2];
#pragma unroll
        for (int mf = 0; mf < 4; ++mf) {
          int row = (mf << 4) + (lane & 15);
          int slot = ((ks << 2) + (lane >> 4)) ^ (row & 7);
          af[mf] = *(bf16x8*)(sA + (row << 7) + (slot << 4));
        }
#pragma unroll
        for (int nf = 0; nf < 2; ++nf) {
          int row = (wv << 5) + (nf << 4) + (lane & 15);
          int slot = ((ks << 2) + (lane >> 4)) ^ (row & 7);
          bfr[nf] = *(bf16x8*)(sB + (row << 7) + (slot << 4));
        }
#pragma unroll
        for (int mf = 0; mf < 4; ++mf)
#pragma unroll
          for (int nf = 0; nf < 2; ++nf)
            acc[mf][nf] = __builtin_amdgcn_mfma_f32_16x16x32_bf16(
                af[mf], bfr[nf], acc[mf][nf], 0, 0, 0);
      }
    }
  }

  // ---- BN partial stats from registers ----
#pragma unroll
  for (int nf = 0; nf < 2; ++nf) {
    float s = 0.f, q = 0.f;
#pragma unroll
    for (int mf = 0; mf < 4; ++mf)
#pragma unroll
      for (int r = 0; r < 4; ++r) {
        float v = acc[mf][nf][r];
        s += v;
        q = fmaf(v, v, q);
      }
    s += __shfl_down(s, 32);
    q += __shfl_down(q, 32);
    s += __shfl_down(s, 16);
    q += __shfl_down(q, 16);
    if (lane < 16) {
      int o = (wv << 5) + (nf << 4) + lane;
      psum[(o << 9) + mblk] = s;
      psq[(o << 9) + mblk] = q;
    }
  }

  // ---- store via LDS transpose, 2 passes of 128 o-rows ----
  __syncthreads();
  for (int p = 0; p < 2; ++p) {
    if ((wv >> 2) == p) {
#pragma unroll
      for (int mf = 0; mf < 4; ++mf)
#pragma unroll
        for (int nf = 0; nf < 2; ++nf) {
          int ro = ((wv & 3) << 5) + (nf << 4) + (lane & 15);
#pragma unroll
          for (int r = 0; r < 4; ++r)
            tr[ro * 65 + (mf << 4) + ((lane >> 4) << 2) + r] = acc[mf][nf][r];
        }
    }
    __syncthreads();
#pragma unroll
    for (int it = 0; it < 4; ++it) {
      int idx = tid + (it << 9);
      int ro = idx >> 4, qd = idx & 15;
      float4 v = make_float4(tr[ro * 65 + qd * 4], tr[ro * 65 + qd * 4 + 1],
                             tr[ro * 65 + qd * 4 + 2], tr[ro * 65 + qd * 4 + 3]);
      *(float4*)(out + (((b << 8) + (p << 7) + ro) << 12) + (h << 6) +
                 (qd << 2)) = v;
    }
    __syncthreads();
  }
}

// ---------------------------------------------------------------------------
// Kernel 3: per-channel stats -> scale/shift (512 partials per channel).
// ---------------------------------------------------------------------------
__global__ __launch_bounds__(64) void k_stats(
    const float* __restrict__ psum, const float* __restrict__ psq,
    const float* __restrict__ gamma, const float* __restrict__ beta,
    float* __restrict__ scale, float* __restrict__ shift) {
  const int o = blockIdx.x;
  const int t = threadIdx.x;
  float s = 0.f, q = 0.f;
#pragma unroll
  for (int i = 0; i < 8; ++i) {
    s += psum[(o << 9) + t + (i << 6)];
    q += psq[(o << 9) + t + (i << 6)];
  }
#pragma unroll
  for (int off = 32; off > 0; off >>= 1) {
    s += __shfl_down(s, off, 64);
    q += __shfl_down(q, off, 64);
  }
  if (t == 0) {
    const float inv_n = 1.f / 32768.f;
    float mean = s * inv_n;
    float var = fmaf(-mean, mean, q * inv_n);
    float sc = gamma[o] * rsqrtf(var + 1e-5f);
    scale[o] = sc;
    shift[o] = fmaf(-mean, sc, beta[o]);
  }
}

// ---------------------------------------------------------------------------
// Kernel 4: in-place BN + ReLU over d_out (float4 elementwise).
// ---------------------------------------------------------------------------
__global__ __launch_bounds__(256) void k_bnrelu(
    float* __restrict__ out, const float* __restrict__ scale,
    const float* __restrict__ shift) {
  int idx = blockIdx.x * 256 + threadIdx.x;
  int o = (idx >> 10) & 255;
  float sc = scale[o], sh = shift[o];
  float4 v = ((float4*)out)[idx];
  v.x = fmaxf(fmaf(v.x, sc, sh), 0.f);
  v.y = fmaxf(fmaf(v.y, sc, sh), 0.f);
  v.z = fmaxf(fmaf(v.z, sc, sh), 0.f);
  v.w = fmaxf(fmaf(v.w, sc, sh), 0.f);
  ((float4*)out)[idx] = v;
}

extern "C" void kernel_launch(void* const* d_in, const int* in_sizes, int n_in,
                              void* d_out, int out_size, void* d_ws,
                              size_t ws_size, hipStream_t stream) {
  const float* x = (const float*)d_in[0];
  const float* ow = (const float*)d_in[1];
  const float* ob = (const float*)d_in[2];
  const float* mw = (const float*)d_in[3];
  const float* mb = (const float*)d_in[4];
  const float* wgt = (const float*)d_in[5];
  // d_in[6] = conv bias: cancels exactly in BN (out - mean(out)), skipped.
  const float* gamma = (const float*)d_in[7];
  const float* beta = (const float*)d_in[8];
  float* out = (float*)d_out;

  float* ws = (float*)d_ws;
  float* dyb = ws;                  // 294912
  float* dxb = dyb + 294912;        // 294912
  float* mskb = dxb + 294912;       // 294912
  float* psum = mskb + 294912;      // 256*512 = 131072
  float* psq = psum + 131072;       // 131072
  float* scale = psq + 131072;      // 256
  float* shift = scale + 256;       // 256
  unsigned short* wT = (unsigned short*)(shift + 256);  // 9*256*256 bf16

  k_wprep<<<256, 256, 0, stream>>>(wgt, wT);
  k_offmod<<<512, 512, 0, stream>>>(x, ow, ob, mw, mb, dyb, dxb, mskb);
  k_main<<<512, 512, 0, stream>>>(x, wT, dyb, dxb, mskb, out, psum, psq);
  k_stats<<<256, 64, 0, stream>>>(psum, psq, gamma, beta, scale, shift);
  k_bnrelu<<<8192, 256, 0, stream>>>(out, scale, shift);
}

// Round 5
// 369.487 us; speedup vs baseline: 1.6900x; 1.0090x over previous
//
#include <hip/hip_runtime.h>
#include <math.h>

#define CI 256
#define CO 256
#define HWN 4096  // H*W

typedef short bf16x8 __attribute__((ext_vector_type(8)));
typedef float f32x4 __attribute__((ext_vector_type(4)));

__device__ inline unsigned pk2(float a, float b) {  // RNE pack 2 f32 -> 2 bf16
  unsigned ua = __float_as_uint(a), ub = __float_as_uint(b);
  ua += 0x7fff + ((ua >> 16) & 1);
  ub += 0x7fff + ((ub >> 16) & 1);
  return (ua >> 16) | (ub & 0xffff0000u);
}

// Raw barrier that does NOT drain vmcnt (keeps A-prefetch loads in flight).
// lgkmcnt(0) makes this wave's ds_writes visible; sched_barrier pins code
// motion; "memory" clobber pins the compiler's memory ops on both sides.
#define PIPE_BARRIER()                                    \
  do {                                                    \
    __builtin_amdgcn_sched_barrier(0);                    \
    asm volatile("s_waitcnt lgkmcnt(0)" ::: "memory");    \
    __builtin_amdgcn_s_barrier();                         \
    __builtin_amdgcn_sched_barrier(0);                    \
  } while (0)

// ---------------------------------------------------------------------------
// Kernel 0: weight pre-transpose+convert: w[o][c][tap] f32 -> wT[tap][o][c] bf16
// ---------------------------------------------------------------------------
__global__ __launch_bounds__(256) void k_wprep(const float* __restrict__ wgt,
                                               unsigned short* __restrict__ wT) {
  const int o = blockIdx.x, c = threadIdx.x;
  const float* wp = wgt + o * 2304 + c * 9;
  float v[9];
#pragma unroll
  for (int t = 0; t < 9; ++t) v[t] = wp[t];
#pragma unroll
  for (int t = 0; t < 9; ++t) {
    unsigned u = __float_as_uint(v[t]);
    u += 0x7fff + ((u >> 16) & 1);
    wT[(t << 16) + (o << 8) + c] = (unsigned short)(u >> 16);
  }
}

// ---------------------------------------------------------------------------
// Kernel 1: offset (18ch) + modulation (9ch) 3x3 conv over Ci=256. Unchanged.
// ---------------------------------------------------------------------------
__global__ __launch_bounds__(512, 4) void k_offmod(
    const float* __restrict__ x, const float* __restrict__ ow,
    const float* __restrict__ ob, const float* __restrict__ mw,
    const float* __restrict__ mb, float* __restrict__ dyb,
    float* __restrict__ dxb, float* __restrict__ mskb) {
  __shared__ float xs[1584];   // 8 ch * 3 rows * 66 cols
  __shared__ float ps[13824];  // 64 px * 27 ch * 8 groups
  const int tid = threadIdx.x;
  const int bh = blockIdx.x;
  const int b = bh >> 6, h = bh & 63;
  const int cg = __builtin_amdgcn_readfirstlane(tid >> 6);  // wave id 0..7
  const int px = tid & 63;
  float acc[27];
#pragma unroll
  for (int i = 0; i < 27; ++i) acc[i] = 0.f;
  const float* xb = x + b * (CI * HWN);
  for (int t = 0; t < 32; ++t) {
    __syncthreads();
    for (int i = tid; i < 1584; i += 512) {
      int cl = i / 198;
      int rem = i - cl * 198;
      int r = rem / 66;
      int col = rem - r * 66 - 1;
      int hh = h - 1 + r;
      float v = 0.f;
      if (hh >= 0 && hh < 64 && col >= 0 && col < 64)
        v = xb[(8 * t + cl) * HWN + hh * 64 + col];
      xs[i] = v;
    }
    __syncthreads();
    float xv[9];
#pragma unroll
    for (int r = 0; r < 3; ++r)
#pragma unroll
      for (int kx = 0; kx < 3; ++kx)
        xv[r * 3 + kx] = xs[cg * 198 + r * 66 + px + kx];
    const int c = 8 * t + cg;
    const float* owp = ow + c * 9;
    const float* mwp = mw + c * 9;
#pragma unroll
    for (int ch = 0; ch < 18; ++ch)
#pragma unroll
      for (int k = 0; k < 9; ++k)
        acc[ch] = fmaf(owp[ch * 2304 + k], xv[k], acc[ch]);
#pragma unroll
    for (int ch = 0; ch < 9; ++ch)
#pragma unroll
      for (int k = 0; k < 9; ++k)
        acc[18 + ch] = fmaf(mwp[ch * 2304 + k], xv[k], acc[18 + ch]);
  }
  __syncthreads();
#pragma unroll
  for (int ch = 0; ch < 27; ++ch) ps[(px * 27 + ch) * 8 + cg] = acc[ch];
  __syncthreads();
  for (int i = tid; i < 1728; i += 512) {
    int p2 = i / 27;
    int ch = i - p2 * 27;
    float s = 0.f;
#pragma unroll
    for (int g = 0; g < 8; ++g) s += ps[i * 8 + g];
    if (ch < 18) {
      s += ob[ch];
      int k = ch >> 1;
      int o9 = ((b * 9 + k) << 12) + (h << 6) + p2;
      if ((ch & 1) == 0) dyb[o9] = s;
      else dxb[o9] = s;
    } else {
      int k = ch - 18;
      s += mb[k];
      mskb[((b * 9 + k) << 12) + (h << 6) + p2] = 2.f / (1.f + expf(-s));
    }
  }
}

// ---------------------------------------------------------------------------
// Kernel 2: bf16-MFMA gather-GEMM, cq-outer/tap-inner (L2-friendly), now
// software-pipelined: chunk t+1's 32 gather loads are issued into registers
// during chunk t's staging phase and stay in flight ACROSS the barriers
// (raw s_barrier + lgkmcnt(0), no vmcnt drain). B-weight loads issue at
// iteration top so their L2 latency hides under the pack VALU.
// ---------------------------------------------------------------------------
__global__ __launch_bounds__(512, 4) void k_main(
    const float* __restrict__ x, const unsigned short* __restrict__ wT,
    const float* __restrict__ dyb, const float* __restrict__ dxb,
    const float* __restrict__ mskb, float* __restrict__ out,
    float* __restrict__ psum, float* __restrict__ psq) {
  __shared__ __align__(16) char smem[50176];
  uint2* s_cw = (uint2*)smem;               // [9][64] 4x bf16 corner w, 4608 B
  ushort4* s_ci = (ushort4*)(smem + 4608);  // [9][64] corner idx, 4608 B
  char* sA = smem + 9216;                   // 64x64 bf16 = 8192 B
  char* sB = smem + 17408;                  // 256x64 bf16 = 32768 B
  float* tr = (float*)(smem + 9216);        // epilogue reuse: 128*65*4 B

  const int tid = threadIdx.x;
  const int mblk = blockIdx.x;  // b*64 + h
  const int b = mblk >> 6, h = mblk & 63;
  const int lane = tid & 63;
  const int wv = tid >> 6;

  // ---- corner table: 9 taps * 64 px ----
  for (int i = tid; i < 576; i += 512) {
    int k = i >> 6, pxi = i & 63;
    int o9 = ((b * 9 + k) << 12) + (h << 6) + pxi;
    float m = mskb[o9];
    float py = (float)(h - 1 + k / 3) + dyb[o9];
    float pxf = (float)(pxi - 1 + k % 3) + dxb[o9];
    float y0f = floorf(py), x0f = floorf(pxf);
    float wy = py - y0f, wx = pxf - x0f;
    int y0 = (int)y0f, x0 = (int)x0f;
    int y1 = y0 + 1, x1 = x0 + 1;
    float w00 = (1.f - wy) * (1.f - wx) * m;
    float w01 = (1.f - wy) * wx * m;
    float w10 = wy * (1.f - wx) * m;
    float w11 = wy * wx * m;
    bool vy0 = ((unsigned)y0 < 64u), vy1 = ((unsigned)y1 < 64u);
    bool vx0 = ((unsigned)x0 < 64u), vx1 = ((unsigned)x1 < 64u);
    if (!(vy0 && vx0)) w00 = 0.f;
    if (!(vy0 && vx1)) w01 = 0.f;
    if (!(vy1 && vx0)) w10 = 0.f;
    if (!(vy1 && vx1)) w11 = 0.f;
    int y0c = min(max(y0, 0), 63), y1c = min(max(y1, 0), 63);
    int x0c = min(max(x0, 0), 63), x1c = min(max(x1, 0), 63);
    s_cw[i] = make_uint2(pk2(w00, w01), pk2(w10, w11));
    s_ci[i] = make_ushort4((unsigned short)(y0c * 64 + x0c),
                           (unsigned short)(y0c * 64 + x1c),
                           (unsigned short)(y1c * 64 + x0c),
                           (unsigned short)(y1c * 64 + x1c));
  }
  __syncthreads();

  f32x4 acc[4][2];
#pragma unroll
  for (int mf = 0; mf < 4; ++mf)
#pragma unroll
    for (int nf = 0; nf < 2; ++nf) acc[mf][nf] = (f32x4){0.f, 0.f, 0.f, 0.f};

  const float* xb = x + b * (CI * HWN);
  const int aslot = (lane << 7) + ((wv ^ (lane & 7)) << 4);
  const int o0 = tid >> 3, seg = tid & 7;
  const int bslot = seg ^ (o0 & 7);  // same for all 4 o-rows (stride 64)

  // ---- prologue: corner regs + A-prefetch for chunk 0 (cq=0, tap=0) ----
  float rx[32];
  float4 cwC;
  {
    uint2 p = s_cw[lane];
    cwC.x = __uint_as_float(p.x << 16);
    cwC.y = __uint_as_float(p.x & 0xffff0000u);
    cwC.z = __uint_as_float(p.y << 16);
    cwC.w = __uint_as_float(p.y & 0xffff0000u);
    ushort4 ci0 = s_ci[lane];
    const float* xpn = xb + (wv << 3) * HWN;
#pragma unroll
    for (int s = 0; s < 8; ++s) {
      const float* xp = xpn + s * HWN;
      rx[4 * s + 0] = xp[ci0.x];
      rx[4 * s + 1] = xp[ci0.y];
      rx[4 * s + 2] = xp[ci0.z];
      rx[4 * s + 3] = xp[ci0.w];
    }
  }

#pragma unroll 1
  for (int t = 0; t < 36; ++t) {
    const int cq = t / 9;
    const int tap = t - cq * 9;
    // ---- issue B loads (L2-resident wT; latency hides under pack VALU) ----
    const unsigned short* wp = wT + (tap << 16) + (cq << 6);
    uint4 rb[4];
#pragma unroll
    for (int r = 0; r < 4; ++r)
      rb[r] = *(const uint4*)(wp + ((o0 + (r << 6)) << 8) + (seg << 3));
    // ---- pack chunk t's prefetched x-values -> sA ----
    {
      unsigned pkv[4];
#pragma unroll
      for (int j2 = 0; j2 < 4; ++j2) {
        float v0 = cwC.x * rx[8 * j2 + 0];
        v0 = fmaf(cwC.y, rx[8 * j2 + 1], v0);
        v0 = fmaf(cwC.z, rx[8 * j2 + 2], v0);
        v0 = fmaf(cwC.w, rx[8 * j2 + 3], v0);
        float v1 = cwC.x * rx[8 * j2 + 4];
        v1 = fmaf(cwC.y, rx[8 * j2 + 5], v1);
        v1 = fmaf(cwC.z, rx[8 * j2 + 6], v1);
        v1 = fmaf(cwC.w, rx[8 * j2 + 7], v1);
        pkv[j2] = pk2(v0, v1);
      }
      *(uint4*)(sA + aslot) = make_uint4(pkv[0], pkv[1], pkv[2], pkv[3]);
    }
    // ---- write B -> sB (waits rb) ----
#pragma unroll
    for (int r = 0; r < 4; ++r)
      *(uint4*)(sB + ((o0 + (r << 6)) << 7) + (bslot << 4)) = rb[r];
    // ---- prefetch chunk t+1: next tap's corner regs + 32 x-loads ----
    {
      const int tn = t < 35 ? t + 1 : 35;  // clamp: last iter reloads (unused)
      const int cqn = tn / 9;
      const int tapn = tn - cqn * 9;
      uint2 p = s_cw[(tapn << 6) + lane];
      float4 cwN;
      cwN.x = __uint_as_float(p.x << 16);
      cwN.y = __uint_as_float(p.x & 0xffff0000u);
      cwN.z = __uint_as_float(p.y << 16);
      cwN.w = __uint_as_float(p.y & 0xffff0000u);
      ushort4 ciN = s_ci[(tapn << 6) + lane];
      const float* xpn = xb + (((cqn << 3) + wv) << 3) * HWN;
#pragma unroll
      for (int s = 0; s < 8; ++s) {
        const float* xp = xpn + s * HWN;
        rx[4 * s + 0] = xp[ciN.x];
        rx[4 * s + 1] = xp[ciN.y];
        rx[4 * s + 2] = xp[ciN.z];
        rx[4 * s + 3] = xp[ciN.w];
      }
      cwC = cwN;
    }
    PIPE_BARRIER();  // sA/sB visible; prefetch loads stay in flight
    // ---- MFMA: 2 k-steps x 4 mfrag x 2 nfrag ----
#pragma unroll
    for (int ks = 0; ks < 2; ++ks) {
      bf16x8 af[4], bfr[2];
#pragma unroll
      for (int mf = 0; mf < 4; ++mf) {
        int row = (mf << 4) + (lane & 15);
        int slot = ((ks << 2) + (lane >> 4)) ^ (row & 7);
        af[mf] = *(bf16x8*)(sA + (row << 7) + (slot << 4));
      }
#pragma unroll
      for (int nf = 0; nf < 2; ++nf) {
        int row = (wv << 5) + (nf << 4) + (lane & 15);
        int slot = ((ks << 2) + (lane >> 4)) ^ (row & 7);
        bfr[nf] = *(bf16x8*)(sB + (row << 7) + (slot << 4));
      }
#pragma unroll
      for (int mf = 0; mf < 4; ++mf)
#pragma unroll
        for (int nf = 0; nf < 2; ++nf)
          acc[mf][nf] = __builtin_amdgcn_mfma_f32_16x16x32_bf16(
              af[mf], bfr[nf], acc[mf][nf], 0, 0, 0);
    }
    PIPE_BARRIER();  // frag reads done before next iteration's writes
  }

  // ---- BN partial stats from registers ----
#pragma unroll
  for (int nf = 0; nf < 2; ++nf) {
    float s = 0.f, q = 0.f;
#pragma unroll
    for (int mf = 0; mf < 4; ++mf)
#pragma unroll
      for (int r = 0; r < 4; ++r) {
        float v = acc[mf][nf][r];
        s += v;
        q = fmaf(v, v, q);
      }
    s += __shfl_down(s, 32);
    q += __shfl_down(q, 32);
    s += __shfl_down(s, 16);
    q += __shfl_down(q, 16);
    if (lane < 16) {
      int o = (wv << 5) + (nf << 4) + lane;
      psum[(o << 9) + mblk] = s;
      psq[(o << 9) + mblk] = q;
    }
  }

  // ---- store via LDS transpose, 2 passes of 128 o-rows ----
  __syncthreads();  // drains leftover prefetch loads too (harmless)
  for (int p = 0; p < 2; ++p) {
    if ((wv >> 2) == p) {
#pragma unroll
      for (int mf = 0; mf < 4; ++mf)
#pragma unroll
        for (int nf = 0; nf < 2; ++nf) {
          int ro = ((wv & 3) << 5) + (nf << 4) + (lane & 15);
#pragma unroll
          for (int r = 0; r < 4; ++r)
            tr[ro * 65 + (mf << 4) + ((lane >> 4) << 2) + r] = acc[mf][nf][r];
        }
    }
    __syncthreads();
#pragma unroll
    for (int it = 0; it < 4; ++it) {
      int idx = tid + (it << 9);
      int ro = idx >> 4, qd = idx & 15;
      float4 v = make_float4(tr[ro * 65 + qd * 4], tr[ro * 65 + qd * 4 + 1],
                             tr[ro * 65 + qd * 4 + 2], tr[ro * 65 + qd * 4 + 3]);
      *(float4*)(out + (((b << 8) + (p << 7) + ro) << 12) + (h << 6) +
                 (qd << 2)) = v;
    }
    __syncthreads();
  }
}

// ---------------------------------------------------------------------------
// Kernel 3: per-channel stats -> scale/shift (512 partials per channel).
// ---------------------------------------------------------------------------
__global__ __launch_bounds__(64) void k_stats(
    const float* __restrict__ psum, const float* __restrict__ psq,
    const float* __restrict__ gamma, const float* __restrict__ beta,
    float* __restrict__ scale, float* __restrict__ shift) {
  const int o = blockIdx.x;
  const int t = threadIdx.x;
  float s = 0.f, q = 0.f;
#pragma unroll
  for (int i = 0; i < 8; ++i) {
    s += psum[(o << 9) + t + (i << 6)];
    q += psq[(o << 9) + t + (i << 6)];
  }
#pragma unroll
  for (int off = 32; off > 0; off >>= 1) {
    s += __shfl_down(s, off, 64);
    q += __shfl_down(q, off, 64);
  }
  if (t == 0) {
    const float inv_n = 1.f / 32768.f;
    float mean = s * inv_n;
    float var = fmaf(-mean, mean, q * inv_n);
    float sc = gamma[o] * rsqrtf(var + 1e-5f);
    scale[o] = sc;
    shift[o] = fmaf(-mean, sc, beta[o]);
  }
}

// ---------------------------------------------------------------------------
// Kernel 4: in-place BN + ReLU over d_out (float4 elementwise).
// ---------------------------------------------------------------------------
__global__ __launch_bounds__(256) void k_bnrelu(
    float* __restrict__ out, const float* __restrict__ scale,
    const float* __restrict__ shift) {
  int idx = blockIdx.x * 256 + threadIdx.x;
  int o = (idx >> 10) & 255;
  float sc = scale[o], sh = shift[o];
  float4 v = ((float4*)out)[idx];
  v.x = fmaxf(fmaf(v.x, sc, sh), 0.f);
  v.y = fmaxf(fmaf(v.y, sc, sh), 0.f);
  v.z = fmaxf(fmaf(v.z, sc, sh), 0.f);
  v.w = fmaxf(fmaf(v.w, sc, sh), 0.f);
  ((float4*)out)[idx] = v;
}

extern "C" void kernel_launch(void* const* d_in, const int* in_sizes, int n_in,
                              void* d_out, int out_size, void* d_ws,
                              size_t ws_size, hipStream_t stream) {
  const float* x = (const float*)d_in[0];
  const float* ow = (const float*)d_in[1];
  const float* ob = (const float*)d_in[2];
  const float* mw = (const float*)d_in[3];
  const float* mb = (const float*)d_in[4];
  const float* wgt = (const float*)d_in[5];
  // d_in[6] = conv bias: cancels exactly in BN (out - mean(out)), skipped.
  const float* gamma = (const float*)d_in[7];
  const float* beta = (const float*)d_in[8];
  float* out = (float*)d_out;

  float* ws = (float*)d_ws;
  float* dyb = ws;                  // 294912
  float* dxb = dyb + 294912;        // 294912
  float* mskb = dxb + 294912;       // 294912
  float* psum = mskb + 294912;      // 256*512 = 131072
  float* psq = psum + 131072;       // 131072
  float* scale = psq + 131072;      // 256
  float* shift = scale + 256;       // 256
  unsigned short* wT = (unsigned short*)(shift + 256);  // 9*256*256 bf16

  k_wprep<<<256, 256, 0, stream>>>(wgt, wT);
  k_offmod<<<512, 512, 0, stream>>>(x, ow, ob, mw, mb, dyb, dxb, mskb);
  k_main<<<512, 512, 0, stream>>>(x, wT, dyb, dxb, mskb, out, psum, psq);
  k_stats<<<256, 64, 0, stream>>>(psum, psq, gamma, beta, scale, shift);
  k_bnrelu<<<8192, 256, 0, stream>>>(out, scale, shift);
}